// Round 1
// baseline (407.508 us; speedup 1.0000x reference)
//
#include <hip/hip_runtime.h>
#include <cfloat>

#define NPTS 16384
#define C_CHUNKS 8
#define CHUNK (NPTS / C_CHUNKS)   // 2048

// packed[dir][j] = (-2*bx, -2*by, -2*bz, |b|^2), dir 0 = target-as-B, dir 1 = output-as-B
__global__ __launch_bounds__(256) void prep_kernel(
    const float* __restrict__ target, const float* __restrict__ output,
    float4* __restrict__ packed, int* __restrict__ minsq, float* __restrict__ out)
{
    int t = blockIdx.x * blockDim.x + threadIdx.x;
    if (t == 0) out[0] = 0.0f;
    if (t < 2 * NPTS) {
        int dir = t >> 14;
        int j = t & (NPTS - 1);
        const float* src = (dir == 0) ? target : output;
        float x = src[3 * j], y = src[3 * j + 1], z = src[3 * j + 2];
        packed[t] = make_float4(-2.f * x, -2.f * y, -2.f * z,
                                fmaf(x, x, fmaf(y, y, z * z)));
        minsq[t] = 0x7F7FFFFF;  // FLT_MAX bit pattern (positive int ordering OK)
    }
}

// dir 0: query = output points vs target (loss_a_to_b); dir 1: query = target vs output
__global__ __launch_bounds__(256) void chamfer_min_kernel(
    const float* __restrict__ target, const float* __restrict__ output,
    const float4* __restrict__ packed, int* __restrict__ minsq)
{
    const int dir = blockIdx.z;
    const int i = blockIdx.x * blockDim.x + threadIdx.x;
    const float* __restrict__ A = (dir == 0) ? output : target;

    const float ax = A[3 * i], ay = A[3 * i + 1], az = A[3 * i + 2];
    const float sqa = fmaf(ax, ax, fmaf(ay, ay, az * az));

    const float4* __restrict__ pk = packed + dir * NPTS + blockIdx.y * CHUNK;

    float m = FLT_MAX;
#pragma unroll 8
    for (int j = 0; j < CHUNK; ++j) {
        float4 p = pk[j];  // wave-uniform address -> broadcast / scalar load
        float s = fmaf(ax, p.x, fmaf(ay, p.y, fmaf(az, p.z, p.w)));
        m = fminf(m, s);
    }
    // min_j d^2 = sqa + min_j(-2 a.b + |b|^2); int-compare valid (values >= -eps)
    atomicMin(&minsq[dir * NPTS + i], __float_as_int(m + sqa));
}

__global__ __launch_bounds__(256) void reduce_kernel(
    const int* __restrict__ minsq, float* __restrict__ out)
{
    int t = blockIdx.x * 256 + threadIdx.x;
    float s = 0.f;
    for (int k = t; k < 2 * NPTS; k += gridDim.x * 256) {
        float v = __int_as_float(minsq[k]);
        s += sqrtf(fmaxf(v, 0.f));
    }
    // wave64 reduce
    for (int off = 32; off; off >>= 1) s += __shfl_down(s, off, 64);
    __shared__ float partial[4];
    int wid = threadIdx.x >> 6;
    if ((threadIdx.x & 63) == 0) partial[wid] = s;
    __syncthreads();
    if (threadIdx.x == 0) {
        float tot = (partial[0] + partial[1]) + (partial[2] + partial[3]);
        atomicAdd(out, tot * 0.001f);
    }
}

extern "C" void kernel_launch(void* const* d_in, const int* in_sizes, int n_in,
                              void* d_out, int out_size, void* d_ws, size_t ws_size,
                              hipStream_t stream) {
    const float* target = (const float*)d_in[0];  // [16384,3]
    const float* output = (const float*)d_in[1];  // [16384,3]
    float* out = (float*)d_out;

    float4* packed = (float4*)d_ws;                                  // 2*NPTS*16 B
    int* minsq = (int*)((char*)d_ws + 2 * NPTS * sizeof(float4));    // 2*NPTS*4 B

    prep_kernel<<<dim3((2 * NPTS + 255) / 256), 256, 0, stream>>>(
        target, output, packed, minsq, out);
    chamfer_min_kernel<<<dim3(NPTS / 256, C_CHUNKS, 2), 256, 0, stream>>>(
        target, output, packed, minsq);
    reduce_kernel<<<32, 256, 0, stream>>>(minsq, out);
}

// Round 2
// 120.128 us; speedup vs baseline: 3.3923x; 3.3923x over previous
//
#include <hip/hip_runtime.h>
#include <cfloat>

#define NPTS 16384
#define C_CHUNKS 16
#define CHUNK (NPTS / C_CHUNKS)   // 1024 points, 16 KB LDS

// packed[dir][j] = (-2*bx, -2*by, -2*bz, |b|^2), dir 0 = target-as-B, dir 1 = output-as-B
__global__ __launch_bounds__(256) void prep_kernel(
    const float* __restrict__ target, const float* __restrict__ output,
    float4* __restrict__ packed, int* __restrict__ minsq, float* __restrict__ out)
{
    int t = blockIdx.x * blockDim.x + threadIdx.x;
    if (t == 0) out[0] = 0.0f;
    if (t < 2 * NPTS) {
        int dir = t >> 14;
        int j = t & (NPTS - 1);
        const float* src = (dir == 0) ? target : output;
        float x = src[3 * j], y = src[3 * j + 1], z = src[3 * j + 2];
        packed[t] = make_float4(-2.f * x, -2.f * y, -2.f * z,
                                fmaf(x, x, fmaf(y, y, z * z)));
        minsq[t] = 0x7F7FFFFF;  // FLT_MAX bits (positive float int-ordering OK)
    }
}

// dir 0: query = output vs target-as-B; dir 1: query = target vs output-as-B
__global__ __launch_bounds__(256) void chamfer_min_kernel(
    const float* __restrict__ target, const float* __restrict__ output,
    const float4* __restrict__ packed, int* __restrict__ minsq)
{
    __shared__ float4 bs[CHUNK];

    const int dir = blockIdx.z;
    const int i = blockIdx.x * blockDim.x + threadIdx.x;
    const float* __restrict__ A = (dir == 0) ? output : target;

    // cooperative coalesced stage of this chunk of B into LDS
    const float4* __restrict__ src = packed + dir * NPTS + blockIdx.y * CHUNK;
    #pragma unroll
    for (int k = 0; k < CHUNK / 256; ++k)
        bs[threadIdx.x + 256 * k] = src[threadIdx.x + 256 * k];

    const float ax = A[3 * i], ay = A[3 * i + 1], az = A[3 * i + 2];
    const float sqa = fmaf(ax, ax, fmaf(ay, ay, az * az));

    __syncthreads();

    // 4 independent accumulators break the serial fmin dependency chain
    float m0 = FLT_MAX, m1 = FLT_MAX, m2 = FLT_MAX, m3 = FLT_MAX;
    #pragma unroll 4
    for (int j = 0; j < CHUNK; j += 4) {
        float4 p0 = bs[j + 0];   // wave-uniform address -> LDS broadcast
        float4 p1 = bs[j + 1];
        float4 p2 = bs[j + 2];
        float4 p3 = bs[j + 3];
        m0 = fminf(m0, fmaf(ax, p0.x, fmaf(ay, p0.y, fmaf(az, p0.z, p0.w))));
        m1 = fminf(m1, fmaf(ax, p1.x, fmaf(ay, p1.y, fmaf(az, p1.z, p1.w))));
        m2 = fminf(m2, fmaf(ax, p2.x, fmaf(ay, p2.y, fmaf(az, p2.z, p2.w))));
        m3 = fminf(m3, fmaf(ax, p3.x, fmaf(ay, p3.y, fmaf(az, p3.z, p3.w))));
    }
    float m = fminf(fminf(m0, m1), fminf(m2, m3));

    // min_j d^2 = sqa + min_j(-2 a.b + |b|^2); int-compare valid (values >= -eps)
    atomicMin(&minsq[dir * NPTS + i], __float_as_int(m + sqa));
}

__global__ __launch_bounds__(256) void reduce_kernel(
    const int* __restrict__ minsq, float* __restrict__ out)
{
    int t = blockIdx.x * 256 + threadIdx.x;
    float s = 0.f;
    for (int k = t; k < 2 * NPTS; k += gridDim.x * 256) {
        float v = __int_as_float(minsq[k]);
        s += sqrtf(fmaxf(v, 0.f));
    }
    for (int off = 32; off; off >>= 1) s += __shfl_down(s, off, 64);
    __shared__ float partial[4];
    int wid = threadIdx.x >> 6;
    if ((threadIdx.x & 63) == 0) partial[wid] = s;
    __syncthreads();
    if (threadIdx.x == 0) {
        float tot = (partial[0] + partial[1]) + (partial[2] + partial[3]);
        atomicAdd(out, tot * 0.001f);
    }
}

extern "C" void kernel_launch(void* const* d_in, const int* in_sizes, int n_in,
                              void* d_out, int out_size, void* d_ws, size_t ws_size,
                              hipStream_t stream) {
    const float* target = (const float*)d_in[0];  // [16384,3]
    const float* output = (const float*)d_in[1];  // [16384,3]
    float* out = (float*)d_out;

    float4* packed = (float4*)d_ws;                                  // 2*NPTS*16 B
    int* minsq = (int*)((char*)d_ws + 2 * NPTS * sizeof(float4));    // 2*NPTS*4 B

    prep_kernel<<<dim3((2 * NPTS + 255) / 256), 256, 0, stream>>>(
        target, output, packed, minsq, out);
    chamfer_min_kernel<<<dim3(NPTS / 256, C_CHUNKS, 2), 256, 0, stream>>>(
        target, output, packed, minsq);
    reduce_kernel<<<32, 256, 0, stream>>>(minsq, out);
}

// Round 3
// 101.287 us; speedup vs baseline: 4.0233x; 1.1860x over previous
//
#include <hip/hip_runtime.h>
#include <cfloat>

#define NPTS 16384
#define C_CHUNKS 32
#define CHUNK (NPTS / C_CHUNKS)   // 512 points, 8 KB LDS
#define NA 4                       // A-points per thread

// dir 0: query = output vs target-as-B; dir 1: query = target vs output-as-B
__global__ __launch_bounds__(256) void chamfer_min_kernel(
    const float* __restrict__ target, const float* __restrict__ output,
    int* __restrict__ minsq)
{
    __shared__ float4 bs[CHUNK];

    const int dir = blockIdx.z;
    const float* __restrict__ A = dir ? target : output;
    const float* __restrict__ B = dir ? output : target;

    // stage + pack this chunk of B: (-2bx, -2by, -2bz, |b|^2)
    const int j0 = blockIdx.y * CHUNK;
    for (int k = threadIdx.x; k < CHUNK; k += 256) {
        int j = j0 + k;
        float x = B[3 * j], y = B[3 * j + 1], z = B[3 * j + 2];
        bs[k] = make_float4(-2.f * x, -2.f * y, -2.f * z,
                            fmaf(x, x, fmaf(y, y, z * z)));
    }

    // 4 A-points per thread: one LDS broadcast feeds 16 independent VALU ops
    const int i0 = blockIdx.x * (256 * NA) + threadIdx.x;
    float ax[NA], ay[NA], az[NA], sqa[NA], m[NA];
    #pragma unroll
    for (int k = 0; k < NA; ++k) {
        int i = i0 + k * 256;
        ax[k] = A[3 * i]; ay[k] = A[3 * i + 1]; az[k] = A[3 * i + 2];
        sqa[k] = fmaf(ax[k], ax[k], fmaf(ay[k], ay[k], az[k] * az[k]));
        m[k] = FLT_MAX;
    }
    __syncthreads();

    #pragma unroll 4
    for (int j = 0; j < CHUNK; ++j) {
        float4 p = bs[j];   // wave-uniform -> LDS broadcast, offset-immediate addressing
        #pragma unroll
        for (int k = 0; k < NA; ++k) {
            float s = fmaf(ax[k], p.x, fmaf(ay[k], p.y, fmaf(az[k], p.z, p.w)));
            m[k] = fminf(m[k], s);
        }
    }

    // min_j d^2 = sqa + min_j(-2 a.b + |b|^2); int-compare valid (values >= -eps)
    #pragma unroll
    for (int k = 0; k < NA; ++k)
        atomicMin(&minsq[dir * NPTS + i0 + k * 256], __float_as_int(m[k] + sqa[k]));
}

__global__ __launch_bounds__(256) void reduce_kernel(
    const int* __restrict__ minsq, float* __restrict__ out)
{
    int t = blockIdx.x * 256 + threadIdx.x;
    float s = 0.f;
    for (int k = t; k < 2 * NPTS; k += gridDim.x * 256) {
        float v = __int_as_float(minsq[k]);
        s += sqrtf(fmaxf(v, 0.f));
    }
    for (int off = 32; off; off >>= 1) s += __shfl_down(s, off, 64);
    __shared__ float partial[4];
    int wid = threadIdx.x >> 6;
    if ((threadIdx.x & 63) == 0) partial[wid] = s;
    __syncthreads();
    if (threadIdx.x == 0) {
        float tot = (partial[0] + partial[1]) + (partial[2] + partial[3]);
        atomicAdd(out, tot * 0.001f);
    }
}

extern "C" void kernel_launch(void* const* d_in, const int* in_sizes, int n_in,
                              void* d_out, int out_size, void* d_ws, size_t ws_size,
                              hipStream_t stream) {
    const float* target = (const float*)d_in[0];  // [16384,3]
    const float* output = (const float*)d_in[1];  // [16384,3]
    float* out = (float*)d_out;

    int* minsq = (int*)d_ws;  // 2*NPTS ints

    // init: minsq bytes 0x7F -> 0x7F7F7F7F, int-orders above any real d^2
    hipMemsetAsync(minsq, 0x7F, 2 * NPTS * sizeof(int), stream);
    hipMemsetAsync(out, 0, sizeof(float), stream);

    chamfer_min_kernel<<<dim3(NPTS / (256 * NA), C_CHUNKS, 2), 256, 0, stream>>>(
        target, output, minsq);
    reduce_kernel<<<32, 256, 0, stream>>>(minsq, out);
}